// Round 8
// baseline (220.498 us; speedup 1.0000x reference)
//
#include <hip/hip_runtime.h>

#define C_IN   672
#define C_OUT  128
#define HW     49
#define XELEMS (C_IN*HW)      // 32928
#define BK     32             // K per step = one MFMA k-step
#define NCH    21             // 672/32
#define CHUNK  (BK*HW)        // 1568 floats per step
#define RS2    40             // hT row stride in halfs (80 B; 16 lanes -> 2-way banks = free)
#define NROWS  64             // padded s dimension
#define SSPAD  680            // 672 + pad for speculative c0+1 read

typedef short  short8 __attribute__((ext_vector_type(8)));
typedef float  f4     __attribute__((ext_vector_type(4)));
typedef float  f2     __attribute__((ext_vector_type(2)));

// Explicit address-space pointers: loads through AS(1) MUST lower to
// global_load_* (vmcnt-only). This guarantees the per-step lgkmcnt(0) is
// wave-local (DS ops only) and can never drain the vmem prefetch queues --
// the suspected shared killer of R8/R10/R11 (flat_* bumps BOTH counters).
typedef const __attribute__((address_space(1))) f4*             gf4p;
typedef const __attribute__((address_space(1))) short8*         gs8p;
typedef const __attribute__((address_space(1))) float*          gfp;
typedef const __attribute__((address_space(1))) unsigned short* gusp;
typedef __attribute__((address_space(1))) float*                gwp;
typedef __attribute__((address_space(3))) unsigned short*       lusp;
typedef const __attribute__((address_space(3))) short8*         ls8p;
typedef const __attribute__((address_space(3))) f2*             lssp;
typedef __attribute__((address_space(3))) unsigned long long*   lu64p;

__device__ __forceinline__ void waitlgkm0() {
    asm volatile("s_waitcnt lgkmcnt(0)" ::: "memory");
}

__device__ __forceinline__ unsigned short f2bf(float f) {
    unsigned u = __float_as_uint(f);
    u += 0x7fffu + ((u >> 16) & 1u);
    return (unsigned short)(u >> 16);
}

__global__ __launch_bounds__(256) void prep_kernel(
        const float* __restrict__ gamma,
        const float* __restrict__ beta,
        const float* __restrict__ rmean,
        const float* __restrict__ rvar,
        const float* __restrict__ W,
        unsigned short* __restrict__ Wbf,
        float* __restrict__ scale,
        float* __restrict__ shift) {
    int i = blockIdx.x * 256 + threadIdx.x;
    if (i < C_IN) {
        float inv = rsqrtf(rvar[i] + 1e-5f);
        float sc  = gamma[i] * inv;
        scale[i] = sc;
        shift[i] = beta[i] - rmean[i] * sc;
    }
    if (i < C_OUT * C_IN) Wbf[i] = f2bf(W[i]);
}

// BN+ReLU+bf16 for one f4, scattered transposed into the wave's PRIVATE hT.
// Plain function with by-value/pointer-typed params: nothing address-taken.
__device__ __forceinline__ void xfrag(f4 xv, int vb, int kb, lusp h, lssp ss,
                                      bool tail) {
    int cb = vb;
    if (tail && cb > CHUNK - 4) cb = CHUNK - 4;   // matches load clamp
    int c0 = cb / HW;                              // magic-div by 49
    int s0 = cb - c0 * HW;
    f2 p0 = ss[kb + c0];
    f2 p1 = ss[kb + c0 + 1];                       // SSPAD covers kb=640,c0=31
    #pragma unroll
    for (int jj = 0; jj < 4; ++jj) {
        int s = s0 + jj, c = c0;
        f2 pp = p0;
        if (s >= HW) { s -= HW; c = c0 + 1; pp = p1; }  // crosses <=1 boundary
        float v = fmaxf(xv[jj] * pp.x + pp.y, 0.f);
        if (!tail || vb + jj < CHUNK)
            h[s * RS2 + c] = f2bf(v);
    }
}

// out_b(128x49) = W(128x672) @ relu(x_b*scale+shift)(672x49).
// R13 == R12 resubmitted verbatim: the R12 round died on container
// acquisition ("MI355X container failed twice"), not on the kernel (full
// OOB/alignment/barrier audit clean). Keeping the source identical so the
// retry measures the R12 hypothesis, not a new variable.
// R12 rationale: five schedules (R5/R7/R8/R10/R11) hit the same ~75us wall;
// two *implementation* hazards were shared by all: (a) staging state touched
// through [&]-lambdas (address-taken -> scratch, proven in R9 by VGPR=56)
// and (b) generic-pointer loads that may lower as flat_* -- which bump
// lgkmcnt, turning every per-step lgkmcnt(0) into a FULL prefetch-queue
// drain. This version removes both by construction: token-pasted macros on
// named scalars (no lambdas, nothing address-taken) and explicit
// address_space(1) loads (guaranteed global_, vmcnt-only).
// Structure: 1 wave = 64 out-rows of one b; 2 waves/b (pair shares x via
// L2, same CU); wave-private hT (5KB LDS, single-buffered -- DS ops of one
// wave execute in order, and lgkmcnt(0) separates write->read). NO barriers
// in the loop: waves drift freely, no convoy. Per step: issue next (7 f4 x
// + 4 short8 W via AS1), transform current in-register, lgkm0, 4 ds_read +
// 16 MFMA. Compiler inserts counted vmcnt per use (SSA, in-order queues).
__global__ __launch_bounds__(256, 2) void gemm_kernel(
        const float* __restrict__ x,
        const unsigned short* __restrict__ Wbf,
        const float* __restrict__ scale,
        const float* __restrict__ shift,
        float* __restrict__ out) {
    __shared__ f2 s_ss[SSPAD];                      // (scale,shift) interleaved
    __shared__ unsigned short hTall[4][NROWS * RS2]; // per-wave private, 4x5KB

    const int tid  = threadIdx.x;
    const int wv   = tid >> 6;           // 0..3
    const int lane = tid & 63;
    const int quad = lane >> 4;
    const int l16  = lane & 15;
    const int b     = blockIdx.x * 2 + (wv >> 1);   // 2 b's per block
    const int mbase = (wv & 1) * 64;                // row half of this wave

    gfp  xg = (gfp)x;
    gusp wg = (gusp)Wbf;
    gwp  og = (gwp)out;
    lusp hl  = (lusp)&hTall[wv][0];
    lssp ssl = (lssp)&s_ss[0];

    // stage s_ss; zero private hT (pad rows 49..63 stay zero: transform
    // only writes s<49). Only barrier in the kernel follows.
    for (int i = tid; i < C_IN; i += 256)
        s_ss[i] = (f2){scale[i], shift[i]};
    if (tid < SSPAD - C_IN) s_ss[C_IN + tid] = (f2){0.f, 0.f};
    for (int i = lane; i < (NROWS * RS2) / 4; i += 64)
        ((lu64p)hl)[i] = 0ull;
    waitlgkm0();
    __builtin_amdgcn_s_barrier();        // s_ss visible to all waves

    const gfp xbp = xg + (size_t)b * XELEMS;
    int t6 = 1536 + lane * 4;
    if (t6 > CHUNK - 4) t6 = CHUNK - 4;  // tail-piece clamp (stores masked)

    // ---- named SSA state, manipulated ONLY via token-pasting macros ----
    f4 xE0, xE1, xE2, xE3, xE4, xE5, xE6;
    f4 xO0, xO1, xO2, xO3, xO4, xO5, xO6;
    short8 aE0, aE1, aE2, aE3, aO0, aO1, aO2, aO3;
    f4 acc00 = {0,0,0,0}, acc01 = {0,0,0,0}, acc02 = {0,0,0,0}, acc03 = {0,0,0,0};
    f4 acc10 = {0,0,0,0}, acc11 = {0,0,0,0}, acc12 = {0,0,0,0}, acc13 = {0,0,0,0};
    f4 acc20 = {0,0,0,0}, acc21 = {0,0,0,0}, acc22 = {0,0,0,0}, acc23 = {0,0,0,0};
    f4 acc30 = {0,0,0,0}, acc31 = {0,0,0,0}, acc32 = {0,0,0,0}, acc33 = {0,0,0,0};

#define ISSUE_X(S, kc) do {                                            \
    gfp _s = xbp + (kc) * CHUNK;                                       \
    x##S##0 = *(gf4p)(_s + lane * 4);                                  \
    x##S##1 = *(gf4p)(_s + 256  + lane * 4);                           \
    x##S##2 = *(gf4p)(_s + 512  + lane * 4);                           \
    x##S##3 = *(gf4p)(_s + 768  + lane * 4);                           \
    x##S##4 = *(gf4p)(_s + 1024 + lane * 4);                           \
    x##S##5 = *(gf4p)(_s + 1280 + lane * 4);                           \
    x##S##6 = *(gf4p)(_s + t6);                                        \
} while (0)

#define ISSUE_A(S, kc) do {                                            \
    gusp _wp = wg + (size_t)(mbase + l16) * C_IN + (kc) * BK + quad * 8; \
    a##S##0 = *(gs8p)(_wp);                                            \
    a##S##1 = *(gs8p)(_wp + 16 * C_IN);                                \
    a##S##2 = *(gs8p)(_wp + 32 * C_IN);                                \
    a##S##3 = *(gs8p)(_wp + 48 * C_IN);                                \
} while (0)

#define TRANSFORM(S, kc) do {                                          \
    const int _kb = (kc) * BK;                                         \
    xfrag(x##S##0, lane * 4,        _kb, hl, ssl, false);              \
    xfrag(x##S##1, 256  + lane * 4, _kb, hl, ssl, false);              \
    xfrag(x##S##2, 512  + lane * 4, _kb, hl, ssl, false);              \
    xfrag(x##S##3, 768  + lane * 4, _kb, hl, ssl, false);              \
    xfrag(x##S##4, 1024 + lane * 4, _kb, hl, ssl, false);              \
    xfrag(x##S##5, 1280 + lane * 4, _kb, hl, ssl, false);              \
    xfrag(x##S##6, 1536 + lane * 4, _kb, hl, ssl, true);               \
} while (0)

#define DOMFMA(S) do {                                                 \
    short8 bv0 = *(ls8p)(hl + (     l16) * RS2 + quad * 8);            \
    short8 bv1 = *(ls8p)(hl + (16 + l16) * RS2 + quad * 8);            \
    short8 bv2 = *(ls8p)(hl + (32 + l16) * RS2 + quad * 8);            \
    short8 bv3 = *(ls8p)(hl + (48 + l16) * RS2 + quad * 8);            \
    acc00 = __builtin_amdgcn_mfma_f32_16x16x32_bf16(a##S##0, bv0, acc00, 0, 0, 0); \
    acc01 = __builtin_amdgcn_mfma_f32_16x16x32_bf16(a##S##0, bv1, acc01, 0, 0, 0); \
    acc02 = __builtin_amdgcn_mfma_f32_16x16x32_bf16(a##S##0, bv2, acc02, 0, 0, 0); \
    acc03 = __builtin_amdgcn_mfma_f32_16x16x32_bf16(a##S##0, bv3, acc03, 0, 0, 0); \
    acc10 = __builtin_amdgcn_mfma_f32_16x16x32_bf16(a##S##1, bv0, acc10, 0, 0, 0); \
    acc11 = __builtin_amdgcn_mfma_f32_16x16x32_bf16(a##S##1, bv1, acc11, 0, 0, 0); \
    acc12 = __builtin_amdgcn_mfma_f32_16x16x32_bf16(a##S##1, bv2, acc12, 0, 0, 0); \
    acc13 = __builtin_amdgcn_mfma_f32_16x16x32_bf16(a##S##1, bv3, acc13, 0, 0, 0); \
    acc20 = __builtin_amdgcn_mfma_f32_16x16x32_bf16(a##S##2, bv0, acc20, 0, 0, 0); \
    acc21 = __builtin_amdgcn_mfma_f32_16x16x32_bf16(a##S##2, bv1, acc21, 0, 0, 0); \
    acc22 = __builtin_amdgcn_mfma_f32_16x16x32_bf16(a##S##2, bv2, acc22, 0, 0, 0); \
    acc23 = __builtin_amdgcn_mfma_f32_16x16x32_bf16(a##S##2, bv3, acc23, 0, 0, 0); \
    acc30 = __builtin_amdgcn_mfma_f32_16x16x32_bf16(a##S##3, bv0, acc30, 0, 0, 0); \
    acc31 = __builtin_amdgcn_mfma_f32_16x16x32_bf16(a##S##3, bv1, acc31, 0, 0, 0); \
    acc32 = __builtin_amdgcn_mfma_f32_16x16x32_bf16(a##S##3, bv2, acc32, 0, 0, 0); \
    acc33 = __builtin_amdgcn_mfma_f32_16x16x32_bf16(a##S##3, bv3, acc33, 0, 0, 0); \
} while (0)

// step K: issue next set -> transform current (compiler: counted vmcnt on
// x(K), leaves K+1 outstanding) -> lgkm0 (DS-only, wave-local) -> MFMA
// (counted vmcnt on a(K)). No barriers: waves fully independent.
#define STEP_E(K) do { ISSUE_X(O, (K) + 1); ISSUE_A(O, (K) + 1); \
    TRANSFORM(E, K); waitlgkm0(); DOMFMA(E); } while (0)
#define STEP_O(K) do { ISSUE_X(E, (K) + 1); ISSUE_A(E, (K) + 1); \
    TRANSFORM(O, K); waitlgkm0(); DOMFMA(O); } while (0)

    ISSUE_X(E, 0); ISSUE_A(E, 0);
    STEP_E(0);  STEP_O(1);  STEP_E(2);  STEP_O(3);  STEP_E(4);
    STEP_O(5);  STEP_E(6);  STEP_O(7);  STEP_E(8);  STEP_O(9);
    STEP_E(10); STEP_O(11); STEP_E(12); STEP_O(13); STEP_E(14);
    STEP_O(15); STEP_E(16); STEP_O(17); STEP_E(18); STEP_O(19);
    TRANSFORM(E, 20); waitlgkm0(); DOMFMA(E);   // last step: no issue

    // epilogue: C/D layout col=lane&15, row=quad*4+reg (m89-verified); mask s>=49
    gwp ob = og + (size_t)b * (C_OUT * HW);
#define EPI(MT, NT, A) do {                                            \
    int _sc = (NT) * 16 + l16;                                         \
    if (_sc < HW) {                                                    \
        gwp _p = ob + (size_t)(mbase + (MT) * 16 + quad * 4) * HW + _sc; \
        _p[0] = A[0]; _p[HW] = A[1]; _p[2 * HW] = A[2]; _p[3 * HW] = A[3]; \
    }                                                                  \
} while (0)
    EPI(0, 0, acc00); EPI(0, 1, acc01); EPI(0, 2, acc02); EPI(0, 3, acc03);
    EPI(1, 0, acc10); EPI(1, 1, acc11); EPI(1, 2, acc12); EPI(1, 3, acc13);
    EPI(2, 0, acc20); EPI(2, 1, acc21); EPI(2, 2, acc22); EPI(2, 3, acc23);
    EPI(3, 0, acc30); EPI(3, 1, acc31); EPI(3, 2, acc32); EPI(3, 3, acc33);
}

extern "C" void kernel_launch(void* const* d_in, const int* in_sizes, int n_in,
                              void* d_out, int out_size, void* d_ws, size_t ws_size,
                              hipStream_t stream) {
    const float* x     = (const float*)d_in[0];
    const float* gamma = (const float*)d_in[1];
    const float* beta  = (const float*)d_in[2];
    const float* rmean = (const float*)d_in[3];
    const float* rvar  = (const float*)d_in[4];
    const float* W     = (const float*)d_in[5];
    float* out = (float*)d_out;

    // ws layout: [bf16 W: 86016*2 B][scale: 672 f32][shift: 672 f32]  (~173 KB)
    unsigned short* Wbf = (unsigned short*)d_ws;
    float* scale = (float*)((char*)d_ws + (size_t)C_OUT * C_IN * 2);
    float* shift = scale + C_IN;

    prep_kernel<<<(C_OUT * C_IN + 255) / 256, 256, 0, stream>>>(
        gamma, beta, rmean, rvar, W, Wbf, scale, shift);
    // 512 blocks x 256 thr: 2 b's per block, 2 blocks/CU, 8 waves/CU
    gemm_kernel<<<512, 256, 0, stream>>>(x, Wbf, scale, shift, out);
}